// Round 4
// baseline (543.465 us; speedup 1.0000x reference)
//
#include <hip/hip_runtime.h>
#include <hip/hip_bf16.h>

typedef __bf16 bf16;
typedef __bf16 bf16x8 __attribute__((ext_vector_type(8)));
typedef __bf16 bf16x4 __attribute__((ext_vector_type(4)));
typedef float  f32x4v __attribute__((ext_vector_type(4)));

#define MFMA16(a, b, c) __builtin_amdgcn_mfma_f32_16x16x32_bf16((a), (b), (c), 0, 0, 0)

static constexpr int D_MODEL = 1024;
static constexpr int NH      = 16;
static constexpr int DK      = 64;
static constexpr int BATCH   = 4;
static constexpr int SEQ     = 2048;

__device__ __forceinline__ void glds16(const void* g, void* l) {
    __builtin_amdgcn_global_load_lds((const __attribute__((address_space(1))) void*)g,
                                     (__attribute__((address_space(3))) void*)l, 16, 0, 0);
}

// ---------------------------------------------------------------------------
// fp32 -> bf16 bulk convert, 7 tensors, grid-stride per tensor
// ---------------------------------------------------------------------------
struct CvtArgs {
    const float* s[7];
    bf16* d[7];
    int n[7];
};

__global__ __launch_bounds__(256) void cvt7(CvtArgs a) {
    const int which = blockIdx.y;
    const int n = a.n[which];
    const float* __restrict__ s = a.s[which];
    bf16* __restrict__ d = a.d[which];
    for (int i = (blockIdx.x * 256 + threadIdx.x) * 8; i < n; i += 512 * 256 * 8) {
        const float4 v0 = *(const float4*)(s + i);
        const float4 v1 = *(const float4*)(s + i + 4);
        bf16x8 o = {(bf16)v0.x, (bf16)v0.y, (bf16)v0.z, (bf16)v0.w,
                    (bf16)v1.x, (bf16)v1.y, (bf16)v1.z, (bf16)v1.w};
        *(bf16x8*)(d + i) = o;
    }
}

// mask int32 [S][S] -> bf16 [S][S]
__global__ __launch_bounds__(256) void mask_prep(const int* __restrict__ m,
                                                 bf16* __restrict__ Mr) {
    const int i = (blockIdx.x * 256 + threadIdx.x) * 8;
    const int4 a = *(const int4*)(m + i);
    const int4 b = *(const int4*)(m + i + 4);
    bf16x8 o = {(bf16)(float)a.x, (bf16)(float)a.y, (bf16)(float)a.z, (bf16)(float)a.w,
                (bf16)(float)b.x, (bf16)(float)b.y, (bf16)(float)b.z, (bf16)(float)b.w};
    *(bf16x8*)(Mr + i) = o;
}

// ---------------------------------------------------------------------------
// Shared GEMM K-loop: C = A @ W^T. 128x128 tile, BK=32, glds16 staging,
// 4 waves of 64x64.
// ---------------------------------------------------------------------------
struct GemmBatch {
    const bf16* A[3];
    const bf16* W[3];
    const float* bias[3];
    bf16* out[3];
};

#define GEMM_KLOOP(Aptr, Wptr)                                                      \
    __shared__ bf16 Als[128 * 32];                                                  \
    __shared__ bf16 Bls[128 * 32];                                                  \
    const int tid  = threadIdx.x;                                                   \
    const int wave = tid >> 6;                                                      \
    const int lane = tid & 63;                                                      \
    const int l15  = lane & 15;                                                     \
    const int quad = lane >> 4;                                                     \
    const int m0   = blockIdx.y * 128;                                              \
    const int n0   = blockIdx.x * 128;                                              \
    const int wm   = (wave >> 1) * 64;                                              \
    const int wn   = (wave & 1) * 64;                                               \
    f32x4v acc[4][4];                                                               \
    _Pragma("unroll") for (int i = 0; i < 4; ++i)                                   \
        _Pragma("unroll") for (int j = 0; j < 4; ++j)                               \
            acc[i][j] = (f32x4v){0.f, 0.f, 0.f, 0.f};                               \
    const int r_a    = wave * 16 + (lane >> 2);                                     \
    const int c_a    = (lane & 3) * 8;                                              \
    const int ldsoff = wave * 512;                                                  \
    for (int k0 = 0; k0 < 1024; k0 += 32) {                                         \
        __syncthreads();                                                            \
        _Pragma("unroll") for (int p = 0; p < 2; ++p) {                             \
            const int row = p * 64 + r_a;                                           \
            glds16(Aptr + (size_t)(m0 + row) * 1024 + k0 + c_a,                     \
                   &Als[p * 2048 + ldsoff]);                                        \
            glds16(Wptr + (size_t)(n0 + row) * 1024 + k0 + c_a,                     \
                   &Bls[p * 2048 + ldsoff]);                                        \
        }                                                                           \
        __syncthreads();                                                            \
        bf16x8 af[4], bfr[4];                                                       \
        _Pragma("unroll") for (int i = 0; i < 4; ++i)                               \
            af[i] = *(const bf16x8*)(&Als[(wm + i * 16 + l15) * 32 + quad * 8]);    \
        _Pragma("unroll") for (int j = 0; j < 4; ++j)                               \
            bfr[j] = *(const bf16x8*)(&Bls[(wn + j * 16 + l15) * 32 + quad * 8]);   \
        _Pragma("unroll") for (int i = 0; i < 4; ++i)                               \
            _Pragma("unroll") for (int j = 0; j < 4; ++j)                           \
                acc[i][j] = MFMA16(af[i], bfr[j], acc[i][j]);                       \
    }

// Fused Q/K/V projection: blockIdx.z selects. z<2 -> head-major [b][h][s][dk];
// z==2 -> V^T [b][h][dk][s].
__global__ __launch_bounds__(256) void gemm_qkv(GemmBatch g) {
    const int z = blockIdx.z;
    const bf16* __restrict__ A = g.A[z];
    const bf16* __restrict__ W = g.W[z];
    GEMM_KLOOP(A, W)
    const float* __restrict__ bias = g.bias[z];
    bf16* __restrict__ out = g.out[z];
#pragma unroll
    for (int j = 0; j < 4; ++j) {
        const int col = n0 + wn + j * 16 + l15;
        const float bs = bias[col];
        const int h = col >> 6, dk = col & 63;
#pragma unroll
        for (int i = 0; i < 4; ++i) {
            const int r4 = m0 + wm + i * 16 + quad * 4;
            const int b = r4 >> 11, sb = r4 & 2047;
            if (z == 2) {
                bf16x4 v = {(bf16)(acc[i][j][0] + bs), (bf16)(acc[i][j][1] + bs),
                            (bf16)(acc[i][j][2] + bs), (bf16)(acc[i][j][3] + bs)};
                *(bf16x4*)(&out[((size_t)((b * NH + h) * 64 + dk)) * SEQ + sb]) = v;
            } else {
#pragma unroll
                for (int reg = 0; reg < 4; ++reg)
                    out[((size_t)(b * NH + h) * SEQ + sb + reg) * 64 + dk] =
                        (bf16)(acc[i][j][reg] + bs);
            }
        }
    }
}

// Output projection: fp32 row-major
__global__ __launch_bounds__(256) void gemm_o(const bf16* __restrict__ A,
                                              const bf16* __restrict__ W,
                                              const float* __restrict__ bias,
                                              float* __restrict__ out) {
    GEMM_KLOOP(A, W)
#pragma unroll
    for (int j = 0; j < 4; ++j) {
        const int col = n0 + wn + j * 16 + l15;
        const float bs = bias[col];
#pragma unroll
        for (int i = 0; i < 4; ++i) {
            const int r4 = m0 + wm + i * 16 + quad * 4;
#pragma unroll
            for (int reg = 0; reg < 4; ++reg)
                out[(size_t)(r4 + reg) * 1024 + col] = acc[i][j][reg] + bs;
        }
    }
}

// ---------------------------------------------------------------------------
// Flash attention, transposed-S dataflow + COALESCED swizzled staging.
// K tile [64 key][64 d] and V^T tile [64 d][64 s] stored row-major in LDS with
// XOR chunk swizzle: 16B-chunk c of row r sits at position c^(r&7). Staging:
// lane l of wave w covers row w*8+(l>>3), global chunk (l&7)^(l>>3) -> K reads
// are fully contiguous 1KB/instr; V reads are 8x128B full segments.
// S^T = K Q^T (A=K, B=Q): lane holds 16 scores for one q-column; exp'd scores
// re-packed IN-REGISTER as the PV B-fragment under k-perm
//   k=quad*8+j <-> t = h*32 + (j>>2)*16 + quad*4 + (j&3),
// V A-frags use the same perm via two b64 reads. 8 waves x 32 q = 256 q/block.
// ---------------------------------------------------------------------------
__global__ __launch_bounds__(512) void attn_kernel(const bf16* __restrict__ Qh,
                                                   const bf16* __restrict__ Kh,
                                                   const bf16* __restrict__ Vtg,
                                                   const bf16* __restrict__ Mr,
                                                   bf16* __restrict__ Xout) {
    __shared__ bf16 Kls[64 * 64];  // [key][d], swizzled chunks
    __shared__ bf16 Vls[64 * 64];  // [d][s], swizzled chunks

    const int tid  = threadIdx.x;
    const int wave = tid >> 6;
    const int lane = tid & 63;
    const int l15  = lane & 15;
    const int quad = lane >> 4;
    const int sw   = l15 & 7;     // row-swizzle key for frag reads
    const int bh   = blockIdx.x;
    const int q0   = blockIdx.y * 256;

    const size_t base = (size_t)bh * SEQ * DK;
    const bf16* Q  = Qh + base;
    const bf16* K  = Kh + base;
    const bf16* Vg = Vtg + base;  // [64][SEQ]

    const int qw = q0 + wave * 32;
    bf16x8 aq[2][2];  // B-frag: [n=q=l15][k=kk*32+quad*8+j]
#pragma unroll
    for (int qb = 0; qb < 2; ++qb)
#pragma unroll
        for (int kk = 0; kk < 2; ++kk)
            aq[qb][kk] = *(const bf16x8*)(Q + (size_t)(qw + qb * 16 + l15) * 64 +
                                          kk * 32 + quad * 8);

    f32x4v acc[2][4];  // O^T: [qb][nt]
    float lsum[2] = {0.f, 0.f};
#pragma unroll
    for (int qb = 0; qb < 2; ++qb)
#pragma unroll
        for (int nt = 0; nt < 4; ++nt) acc[qb][nt] = (f32x4v){0.f, 0.f, 0.f, 0.f};

    constexpr float CLOG = 0.125f * 1.4426950408889634f;
    const bf16* mrow = Mr + (size_t)(qw + l15) * 2048 + quad * 4;

    // staging map: row = wave*8 + (lane>>3), position lane&7 holds chunk (lane&7)^(row&7)
    const int s_r8 = lane >> 3;
    const int s_cg = (lane & 7) ^ s_r8;
    const int s_row = wave * 8 + s_r8;

    for (int kt = 0; kt < SEQ; kt += 64) {
        __syncthreads();
        glds16(K + (size_t)(kt + s_row) * 64 + s_cg * 8, &Kls[wave * 512]);
        glds16(Vg + (size_t)s_row * SEQ + kt + s_cg * 8, &Vls[wave * 512]);
        bf16x4 mv[2][4];  // mask[q][kt + t16*16 + quad*4 + r]
#pragma unroll
        for (int qb = 0; qb < 2; ++qb)
#pragma unroll
            for (int t16 = 0; t16 < 4; ++t16)
                mv[qb][t16] = *(const bf16x4*)(mrow + qb * 16 * 2048 + kt + t16 * 16);
        __syncthreads();

        // S^T = K Q^T : A-frag = K[t16*16+l15][kk*32+quad*8+..] (swizzled)
        f32x4v sv[2][4];
#pragma unroll
        for (int qb = 0; qb < 2; ++qb)
#pragma unroll
            for (int t16 = 0; t16 < 4; ++t16) sv[qb][t16] = (f32x4v){0.f, 0.f, 0.f, 0.f};
#pragma unroll
        for (int kk = 0; kk < 2; ++kk) {
#pragma unroll
            for (int t16 = 0; t16 < 4; ++t16) {
                const bf16x8 bk = *(const bf16x8*)(
                    &Kls[(t16 * 16 + l15) * 64 + (((kk * 4 + quad) ^ sw) * 8)]);
                sv[0][t16] = MFMA16(bk, aq[0][kk], sv[0][t16]);
                sv[1][t16] = MFMA16(bk, aq[1][kk], sv[1][t16]);
            }
        }

        // exp + mask; pack directly into PV B-frags (k-permuted)
        bf16x8 pf[2][2];  // [qb][h]
#pragma unroll
        for (int qb = 0; qb < 2; ++qb) {
#pragma unroll
            for (int h = 0; h < 2; ++h) {
#pragma unroll
                for (int t16h = 0; t16h < 2; ++t16h) {
                    const int t16 = 2 * h + t16h;
#pragma unroll
                    for (int r = 0; r < 4; ++r) {
                        const float e = exp2f(sv[qb][t16][r] * CLOG) *
                                        (float)mv[qb][t16][r];
                        lsum[qb] += e;
                        pf[qb][h][t16h * 4 + r] = (bf16)e;
                    }
                }
            }
        }

        // O^T += V^T P^T : A-frag rows d, two b64 reads per h (perm match)
#pragma unroll
        for (int nt = 0; nt < 4; ++nt) {
            const int dbase = (nt * 16 + l15) * 64;
            const int qoff = (quad & 1) * 4;
            const int qh = quad >> 1;
#pragma unroll
            for (int h = 0; h < 2; ++h) {
                const bf16x4 v0 = *(const bf16x4*)(
                    &Vls[dbase + ((4 * h + qh) ^ sw) * 8 + qoff]);
                const bf16x4 v1 = *(const bf16x4*)(
                    &Vls[dbase + ((4 * h + 2 + qh) ^ sw) * 8 + qoff]);
                const bf16x8 va = {v0[0], v0[1], v0[2], v0[3],
                                   v1[0], v1[1], v1[2], v1[3]};
                acc[0][nt] = MFMA16(va, pf[0][h], acc[0][nt]);
                acc[1][nt] = MFMA16(va, pf[1][h], acc[1][nt]);
            }
        }
    }

    // normalize (reduce partial sums across quads) and store O^T:
    // col=q=l15, row=d=quad*4+reg -> bf16x4 stores along d.
    const int b = bh >> 4, h = bh & 15;
#pragma unroll
    for (int qb = 0; qb < 2; ++qb) {
        float l = lsum[qb];
        l += __shfl_xor(l, 16, 64);
        l += __shfl_xor(l, 32, 64);
        const float rinv = 1.0f / l;
        const size_t rowoff = (size_t)(b * SEQ + qw + qb * 16 + l15) * D_MODEL;
#pragma unroll
        for (int nt = 0; nt < 4; ++nt) {
            bf16x4 o = {(bf16)(acc[qb][nt][0] * rinv), (bf16)(acc[qb][nt][1] * rinv),
                        (bf16)(acc[qb][nt][2] * rinv), (bf16)(acc[qb][nt][3] * rinv)};
            *(bf16x4*)(&Xout[rowoff + h * 64 + nt * 16 + quad * 4]) = o;
        }
    }
}

extern "C" void kernel_launch(void* const* d_in, const int* in_sizes, int n_in,
                              void* d_out, int out_size, void* d_ws, size_t ws_size,
                              hipStream_t stream) {
    const float* q    = (const float*)d_in[0];
    const float* k    = (const float*)d_in[1];
    const float* v    = (const float*)d_in[2];
    const int*   mask = (const int*)d_in[3];
    const float* Wq   = (const float*)d_in[4];
    const float* bq   = (const float*)d_in[5];
    const float* Wk   = (const float*)d_in[6];
    const float* bk   = (const float*)d_in[7];
    const float* Wv   = (const float*)d_in[8];
    const float* bv   = (const float*)d_in[9];
    const float* Wo   = (const float*)d_in[10];
    const float* bo   = (const float*)d_in[11];

    const size_t T = (size_t)BATCH * SEQ * D_MODEL;
    const size_t WN = (size_t)D_MODEL * D_MODEL;
    char* w = (char*)d_ws;
    bf16* Qh  = (bf16*)w; w += T * 2;
    bf16* Kh  = (bf16*)w; w += T * 2;
    bf16* Vt  = (bf16*)w; w += T * 2;
    bf16* Mr  = (bf16*)w; w += (size_t)SEQ * SEQ * 2;
    bf16* qb2 = (bf16*)w; w += T * 2;  // reused as attn output X
    bf16* kb2 = (bf16*)w; w += T * 2;
    bf16* vb2 = (bf16*)w; w += T * 2;
    bf16* Wqb = (bf16*)w; w += WN * 2;
    bf16* Wkb = (bf16*)w; w += WN * 2;
    bf16* Wvb = (bf16*)w; w += WN * 2;
    bf16* Wob = (bf16*)w; w += WN * 2;

    CvtArgs ca;
    ca.s[0] = q;  ca.d[0] = qb2; ca.n[0] = (int)T;
    ca.s[1] = k;  ca.d[1] = kb2; ca.n[1] = (int)T;
    ca.s[2] = v;  ca.d[2] = vb2; ca.n[2] = (int)T;
    ca.s[3] = Wq; ca.d[3] = Wqb; ca.n[3] = (int)WN;
    ca.s[4] = Wk; ca.d[4] = Wkb; ca.n[4] = (int)WN;
    ca.s[5] = Wv; ca.d[5] = Wvb; ca.n[5] = (int)WN;
    ca.s[6] = Wo; ca.d[6] = Wob; ca.n[6] = (int)WN;
    cvt7<<<dim3(512, 7), 256, 0, stream>>>(ca);
    mask_prep<<<dim3((SEQ * SEQ) / 2048), 256, 0, stream>>>(mask, Mr);

    GemmBatch g;
    g.A[0] = qb2; g.W[0] = Wqb; g.bias[0] = bq; g.out[0] = Qh;
    g.A[1] = kb2; g.W[1] = Wkb; g.bias[1] = bk; g.out[1] = Kh;
    g.A[2] = vb2; g.W[2] = Wvb; g.bias[2] = bv; g.out[2] = Vt;
    gemm_qkv<<<dim3(D_MODEL / 128, (BATCH * SEQ) / 128, 3), 256, 0, stream>>>(g);

    attn_kernel<<<dim3(BATCH * NH, SEQ / 256), 512, 0, stream>>>(Qh, Kh, Vt, Mr, qb2);

    gemm_o<<<dim3(D_MODEL / 128, (BATCH * SEQ) / 128), 256, 0, stream>>>(qb2, Wob, bo,
                                                                         (float*)d_out);
}

// Round 5
// 496.720 us; speedup vs baseline: 1.0941x; 1.0941x over previous
//
#include <hip/hip_runtime.h>
#include <hip/hip_bf16.h>

typedef __bf16 bf16;
typedef __bf16 bf16x8 __attribute__((ext_vector_type(8)));
typedef __bf16 bf16x4 __attribute__((ext_vector_type(4)));
typedef float  f32x4v __attribute__((ext_vector_type(4)));

#define MFMA16(a, b, c) __builtin_amdgcn_mfma_f32_16x16x32_bf16((a), (b), (c), 0, 0, 0)

static constexpr int D_MODEL = 1024;
static constexpr int NH      = 16;
static constexpr int DK      = 64;
static constexpr int BATCH   = 4;
static constexpr int SEQ     = 2048;

__device__ __forceinline__ void glds16(const void* g, void* l) {
    __builtin_amdgcn_global_load_lds((const __attribute__((address_space(1))) void*)g,
                                     (__attribute__((address_space(3))) void*)l, 16, 0, 0);
}

// ---------------------------------------------------------------------------
// fp32 -> bf16 bulk convert, 7 tensors, grid-stride per tensor
// ---------------------------------------------------------------------------
struct CvtArgs {
    const float* s[7];
    bf16* d[7];
    int n[7];
};

__global__ __launch_bounds__(256) void cvt7(CvtArgs a) {
    const int which = blockIdx.y;
    const int n = a.n[which];
    const float* __restrict__ s = a.s[which];
    bf16* __restrict__ d = a.d[which];
    for (int i = (blockIdx.x * 256 + threadIdx.x) * 8; i < n; i += 512 * 256 * 8) {
        const float4 v0 = *(const float4*)(s + i);
        const float4 v1 = *(const float4*)(s + i + 4);
        bf16x8 o = {(bf16)v0.x, (bf16)v0.y, (bf16)v0.z, (bf16)v0.w,
                    (bf16)v1.x, (bf16)v1.y, (bf16)v1.z, (bf16)v1.w};
        *(bf16x8*)(d + i) = o;
    }
}

// ---------------------------------------------------------------------------
// mask int32 [S][S] -> fp32 additive-log mask, interleaved:
// Mlog[row][g*64 + l15*4 + ch] = (mask[row][g*64 + ch*16 + l15]==0) ? -20000 : 0
// An attn lane then reads its 4 values for a 64-key group as one float4.
// ---------------------------------------------------------------------------
__global__ __launch_bounds__(256) void mask_prep(const int* __restrict__ m,
                                                 float* __restrict__ Mlog) {
    const int o = blockIdx.x * 256 + threadIdx.x;  // 0 .. S*S-1
    const int row = o >> 11, j = o & 2047;
    const int g = j >> 6, idx = j & 63;
    const int incol = (g << 6) + ((idx & 3) << 4) + (idx >> 2);
    Mlog[o] = (m[row * 2048 + incol] == 0) ? -20000.0f : 0.0f;
}

// ---------------------------------------------------------------------------
// Shared GEMM K-loop: C = A @ W^T. 128x128 tile, BK=32, glds16 staging,
// 4 waves of 64x64.
// ---------------------------------------------------------------------------
struct GemmBatch {
    const bf16* A[3];
    const bf16* W[3];
    const float* bias[3];
    bf16* out[3];
};

#define GEMM_KLOOP(Aptr, Wptr)                                                      \
    __shared__ bf16 Als[128 * 32];                                                  \
    __shared__ bf16 Bls[128 * 32];                                                  \
    const int tid  = threadIdx.x;                                                   \
    const int wave = tid >> 6;                                                      \
    const int lane = tid & 63;                                                      \
    const int l15  = lane & 15;                                                     \
    const int quad = lane >> 4;                                                     \
    const int m0   = blockIdx.y * 128;                                              \
    const int n0   = blockIdx.x * 128;                                              \
    const int wm   = (wave >> 1) * 64;                                              \
    const int wn   = (wave & 1) * 64;                                               \
    f32x4v acc[4][4];                                                               \
    _Pragma("unroll") for (int i = 0; i < 4; ++i)                                   \
        _Pragma("unroll") for (int j = 0; j < 4; ++j)                               \
            acc[i][j] = (f32x4v){0.f, 0.f, 0.f, 0.f};                               \
    const int r_a    = wave * 16 + (lane >> 2);                                     \
    const int c_a    = (lane & 3) * 8;                                              \
    const int ldsoff = wave * 512;                                                  \
    for (int k0 = 0; k0 < 1024; k0 += 32) {                                         \
        __syncthreads();                                                            \
        _Pragma("unroll") for (int p = 0; p < 2; ++p) {                             \
            const int row = p * 64 + r_a;                                           \
            glds16(Aptr + (size_t)(m0 + row) * 1024 + k0 + c_a,                     \
                   &Als[p * 2048 + ldsoff]);                                        \
            glds16(Wptr + (size_t)(n0 + row) * 1024 + k0 + c_a,                     \
                   &Bls[p * 2048 + ldsoff]);                                        \
        }                                                                           \
        __syncthreads();                                                            \
        bf16x8 af[4], bfr[4];                                                       \
        _Pragma("unroll") for (int i = 0; i < 4; ++i)                               \
            af[i] = *(const bf16x8*)(&Als[(wm + i * 16 + l15) * 32 + quad * 8]);    \
        _Pragma("unroll") for (int j = 0; j < 4; ++j)                               \
            bfr[j] = *(const bf16x8*)(&Bls[(wn + j * 16 + l15) * 32 + quad * 8]);   \
        _Pragma("unroll") for (int i = 0; i < 4; ++i)                               \
            _Pragma("unroll") for (int j = 0; j < 4; ++j)                           \
                acc[i][j] = MFMA16(af[i], bfr[j], acc[i][j]);                       \
    }

// Fused Q/K/V projection: blockIdx.z selects. z<2 -> head-major [b][h][s][dk];
// z==2 -> V^T [b][h][dk][s].
__global__ __launch_bounds__(256) void gemm_qkv(GemmBatch g) {
    const int z = blockIdx.z;
    const bf16* __restrict__ A = g.A[z];
    const bf16* __restrict__ W = g.W[z];
    GEMM_KLOOP(A, W)
    const float* __restrict__ bias = g.bias[z];
    bf16* __restrict__ out = g.out[z];
#pragma unroll
    for (int j = 0; j < 4; ++j) {
        const int col = n0 + wn + j * 16 + l15;
        const float bs = bias[col];
        const int h = col >> 6, dk = col & 63;
#pragma unroll
        for (int i = 0; i < 4; ++i) {
            const int r4 = m0 + wm + i * 16 + quad * 4;
            const int b = r4 >> 11, sb = r4 & 2047;
            if (z == 2) {
                bf16x4 v = {(bf16)(acc[i][j][0] + bs), (bf16)(acc[i][j][1] + bs),
                            (bf16)(acc[i][j][2] + bs), (bf16)(acc[i][j][3] + bs)};
                *(bf16x4*)(&out[((size_t)((b * NH + h) * 64 + dk)) * SEQ + sb]) = v;
            } else {
#pragma unroll
                for (int reg = 0; reg < 4; ++reg)
                    out[((size_t)(b * NH + h) * SEQ + sb + reg) * 64 + dk] =
                        (bf16)(acc[i][j][reg] + bs);
            }
        }
    }
}

// Output projection: fp32 row-major
__global__ __launch_bounds__(256) void gemm_o(const bf16* __restrict__ A,
                                              const bf16* __restrict__ W,
                                              const float* __restrict__ bias,
                                              float* __restrict__ out) {
    GEMM_KLOOP(A, W)
#pragma unroll
    for (int j = 0; j < 4; ++j) {
        const int col = n0 + wn + j * 16 + l15;
        const float bs = bias[col];
#pragma unroll
        for (int i = 0; i < 4; ++i) {
            const int r4 = m0 + wm + i * 16 + quad * 4;
#pragma unroll
            for (int reg = 0; reg < 4; ++reg)
                out[(size_t)(r4 + reg) * 1024 + col] = acc[i][j][reg] + bs;
        }
    }
}

// ---------------------------------------------------------------------------
// Flash attention — R2 structure (measured 175.8us) + KT=128 + additive mask.
// 4 waves x 64 q-rows = 256 q/block. Key tiles of 128, processed as two
// 64-key halves (PV after each half, reusing a 64-wide per-wave P buffer;
// P write->read is same-wave, no barrier). Chunk-major K/V LDS (measured
// conflict-free). Softmax is fixed-max (exact: scores bounded) with the mask
// folded in additively: e = exp2(fma(s, CLOG, mlog)), mlog in {0,-20000}.
// ---------------------------------------------------------------------------
__global__ __launch_bounds__(256, 2) void attn_kernel(const bf16* __restrict__ Qh,
                                                      const bf16* __restrict__ Kh,
                                                      const bf16* __restrict__ Vtg,
                                                      const float* __restrict__ Mlog,
                                                      bf16* __restrict__ Xout) {
    __shared__ bf16 Kls[8 * 128 * 8];   // [kc=d/8][key 0..127][8]   16 KB
    __shared__ bf16 Vls[16 * 64 * 8];   // [sc=s/8][d 0..63][8]      16 KB
    __shared__ bf16 Pls[256 * 72];      // 4 waves x 64 q-rows, 64 keys + pad  36 KB

    const int tid  = threadIdx.x;
    const int wave = tid >> 6;
    const int lane = tid & 63;
    const int l15  = lane & 15;
    const int quad = lane >> 4;
    const int bh   = blockIdx.x;
    const int q0   = blockIdx.y * 256;

    const size_t base = (size_t)bh * SEQ * DK;
    const bf16* Q  = Qh + base;
    const bf16* K  = Kh + base;
    const bf16* Vg = Vtg + base;  // [64][SEQ]

    const int qw = q0 + wave * 64;
    // Q A-frags: [rb][kk], m = l15, k = kk*32 + quad*8 + j
    bf16x8 aq[4][2];
#pragma unroll
    for (int rb = 0; rb < 4; ++rb)
#pragma unroll
        for (int kk = 0; kk < 2; ++kk)
            aq[rb][kk] = *(const bf16x8*)(Q + (size_t)(qw + rb * 16 + l15) * 64 +
                                          kk * 32 + quad * 8);

    f32x4v acc[4][4];  // [rb][nt]
    float lsum[4][4];  // [rb][reg]
#pragma unroll
    for (int rb = 0; rb < 4; ++rb)
#pragma unroll
        for (int x = 0; x < 4; ++x) {
            acc[rb][x] = (f32x4v){0.f, 0.f, 0.f, 0.f};
            lsum[rb][x] = 0.f;
        }

    constexpr float CLOG = 0.125f * 1.4426950408889634f;  // 1/sqrt(dk) * log2(e)
    // per (rb,reg): row = qw + rb*16 + quad*4 + reg; float4 at + kt + hf*64
    const float* mrow = Mlog + (size_t)(qw + quad * 4) * 2048 + l15 * 4;

    for (int kt = 0; kt < SEQ; kt += 128) {
        __syncthreads();
        // stage K tile 128x64 (chunk-major) and V^T tile 64x128 (s-chunk-major)
#pragma unroll
        for (int p = 0; p < 2; ++p) {
            const int kc = wave * 2 + p;
#pragma unroll
            for (int h2 = 0; h2 < 2; ++h2)
                glds16(K + (size_t)(kt + h2 * 64 + lane) * 64 + kc * 8,
                       &Kls[kc * 1024 + h2 * 512]);
        }
#pragma unroll
        for (int p = 0; p < 4; ++p) {
            const int sc = wave * 4 + p;
            glds16(Vg + (size_t)lane * SEQ + kt + sc * 8, &Vls[sc * 512]);
        }
        __syncthreads();

#pragma unroll
        for (int hf = 0; hf < 2; ++hf) {
            // K B-frags for this half: [n16][kk], n = l15 (key), k = quad*8+j
            bf16x8 bk[4][2];
#pragma unroll
            for (int n16 = 0; n16 < 4; ++n16)
#pragma unroll
                for (int kk = 0; kk < 2; ++kk)
                    bk[n16][kk] = *(const bf16x8*)(
                        &Kls[(kk * 4 + quad) * 1024 + (hf * 64 + n16 * 16 + l15) * 8]);

#pragma unroll
            for (int rb = 0; rb < 4; ++rb) {
                // mask values: [reg] float4, component = n16
                float4 mv[4];
#pragma unroll
                for (int reg = 0; reg < 4; ++reg)
                    mv[reg] = *(const float4*)(mrow + (size_t)(rb * 16 + reg) * 2048 +
                                               kt + hf * 64);
                // S scores for this rb
                f32x4v sv[4];
#pragma unroll
                for (int n16 = 0; n16 < 4; ++n16) {
                    f32x4v t = (f32x4v){0.f, 0.f, 0.f, 0.f};
                    t = MFMA16(aq[rb][0], bk[n16][0], t);
                    t = MFMA16(aq[rb][1], bk[n16][1], t);
                    sv[n16] = t;
                }
                const int prow0 = wave * 64 + rb * 16 + quad * 4;
#pragma unroll
                for (int reg = 0; reg < 4; ++reg) {
                    const float* ml = (const float*)&mv[reg];
#pragma unroll
                    for (int n16 = 0; n16 < 4; ++n16) {
                        const float e = exp2f(fmaf(sv[n16][reg], CLOG, ml[n16]));
                        lsum[rb][reg] += e;
                        Pls[(prow0 + reg) * 72 + n16 * 16 + l15] = (bf16)e;
                    }
                }
            }

            // P A-frags (same-wave round trip): [rb][kc2]
            bf16x8 pf[4][2];
#pragma unroll
            for (int rb = 0; rb < 4; ++rb)
#pragma unroll
                for (int kc2 = 0; kc2 < 2; ++kc2)
                    pf[rb][kc2] = *(const bf16x8*)(
                        &Pls[(wave * 64 + rb * 16 + l15) * 72 + kc2 * 32 + quad * 8]);
            // O += P V
#pragma unroll
            for (int nt = 0; nt < 4; ++nt) {
                const bf16x8 bv0 = *(const bf16x8*)(
                    &Vls[((hf * 8 + quad) * 64 + nt * 16 + l15) * 8]);
                const bf16x8 bv1 = *(const bf16x8*)(
                    &Vls[((hf * 8 + 4 + quad) * 64 + nt * 16 + l15) * 8]);
#pragma unroll
                for (int rb = 0; rb < 4; ++rb) {
                    acc[rb][nt] = MFMA16(pf[rb][0], bv0, acc[rb][nt]);
                    acc[rb][nt] = MFMA16(pf[rb][1], bv1, acc[rb][nt]);
                }
            }
        }
    }

    // normalize and write X row-major bf16 [B*S][D_MODEL]
    const int b = bh >> 4, h = bh & 15;
#pragma unroll
    for (int rb = 0; rb < 4; ++rb) {
        float rinv[4];
#pragma unroll
        for (int reg = 0; reg < 4; ++reg) {
            float l = lsum[rb][reg];
            l += __shfl_xor(l, 1, 16);
            l += __shfl_xor(l, 2, 16);
            l += __shfl_xor(l, 4, 16);
            l += __shfl_xor(l, 8, 16);
            rinv[reg] = 1.0f / l;
        }
#pragma unroll
        for (int nt = 0; nt < 4; ++nt)
#pragma unroll
            for (int reg = 0; reg < 4; ++reg) {
                const int sg = qw + rb * 16 + quad * 4 + reg;
                Xout[(size_t)(b * SEQ + sg) * D_MODEL + h * 64 + nt * 16 + l15] =
                    (bf16)(acc[rb][nt][reg] * rinv[reg]);
            }
    }
}

extern "C" void kernel_launch(void* const* d_in, const int* in_sizes, int n_in,
                              void* d_out, int out_size, void* d_ws, size_t ws_size,
                              hipStream_t stream) {
    const float* q    = (const float*)d_in[0];
    const float* k    = (const float*)d_in[1];
    const float* v    = (const float*)d_in[2];
    const int*   mask = (const int*)d_in[3];
    const float* Wq   = (const float*)d_in[4];
    const float* bq   = (const float*)d_in[5];
    const float* Wk   = (const float*)d_in[6];
    const float* bk   = (const float*)d_in[7];
    const float* Wv   = (const float*)d_in[8];
    const float* bv   = (const float*)d_in[9];
    const float* Wo   = (const float*)d_in[10];
    const float* bo   = (const float*)d_in[11];

    const size_t T = (size_t)BATCH * SEQ * D_MODEL;
    const size_t WN = (size_t)D_MODEL * D_MODEL;
    char* w = (char*)d_ws;
    bf16* Qh  = (bf16*)w; w += T * 2;
    bf16* Kh  = (bf16*)w; w += T * 2;
    bf16* Vt  = (bf16*)w; w += T * 2;
    bf16* qb2 = (bf16*)w; w += T * 2;  // reused as attn output X
    bf16* kb2 = (bf16*)w; w += T * 2;  // reused as Mlog (fp32, 16.78 MB) after gemm_qkv
    bf16* vb2 = (bf16*)w; w += T * 2;
    bf16* Wqb = (bf16*)w; w += WN * 2;
    bf16* Wkb = (bf16*)w; w += WN * 2;
    bf16* Wvb = (bf16*)w; w += WN * 2;
    bf16* Wob = (bf16*)w; w += WN * 2;
    float* Mlog = (float*)kb2;  // SEQ*SEQ*4 B == T*2 B exactly

    CvtArgs ca;
    ca.s[0] = q;  ca.d[0] = qb2; ca.n[0] = (int)T;
    ca.s[1] = k;  ca.d[1] = kb2; ca.n[1] = (int)T;
    ca.s[2] = v;  ca.d[2] = vb2; ca.n[2] = (int)T;
    ca.s[3] = Wq; ca.d[3] = Wqb; ca.n[3] = (int)WN;
    ca.s[4] = Wk; ca.d[4] = Wkb; ca.n[4] = (int)WN;
    ca.s[5] = Wv; ca.d[5] = Wvb; ca.n[5] = (int)WN;
    ca.s[6] = Wo; ca.d[6] = Wob; ca.n[6] = (int)WN;
    cvt7<<<dim3(512, 7), 256, 0, stream>>>(ca);

    GemmBatch g;
    g.A[0] = qb2; g.W[0] = Wqb; g.bias[0] = bq; g.out[0] = Qh;
    g.A[1] = kb2; g.W[1] = Wkb; g.bias[1] = bk; g.out[1] = Kh;
    g.A[2] = vb2; g.W[2] = Wvb; g.bias[2] = bv; g.out[2] = Vt;
    gemm_qkv<<<dim3(D_MODEL / 128, (BATCH * SEQ) / 128, 3), 256, 0, stream>>>(g);

    // kb2 is dead now; build the additive mask in its place
    mask_prep<<<dim3((SEQ * SEQ) / 256), 256, 0, stream>>>(mask, Mlog);

    attn_kernel<<<dim3(BATCH * NH, SEQ / 256), 256, 0, stream>>>(Qh, Kh, Vt, Mlog, qb2);

    gemm_o<<<dim3(D_MODEL / 128, (BATCH * SEQ) / 128), 256, 0, stream>>>(qb2, Wob, bo,
                                                                         (float*)d_out);
}

// Round 6
// 468.519 us; speedup vs baseline: 1.1600x; 1.0602x over previous
//
#include <hip/hip_runtime.h>
#include <hip/hip_bf16.h>

typedef __bf16 bf16;
typedef __bf16 bf16x8 __attribute__((ext_vector_type(8)));
typedef __bf16 bf16x4 __attribute__((ext_vector_type(4)));
typedef float  f32x4v __attribute__((ext_vector_type(4)));

#define MFMA16(a, b, c) __builtin_amdgcn_mfma_f32_16x16x32_bf16((a), (b), (c), 0, 0, 0)

static constexpr int D_MODEL = 1024;
static constexpr int NH      = 16;
static constexpr int DK      = 64;
static constexpr int BATCH   = 4;
static constexpr int SEQ     = 2048;

__device__ __forceinline__ void glds16(const void* g, void* l) {
    __builtin_amdgcn_global_load_lds((const __attribute__((address_space(1))) void*)g,
                                     (__attribute__((address_space(3))) void*)l, 16, 0, 0);
}

// ---------------------------------------------------------------------------
// fp32 -> bf16 bulk convert, 7 tensors, grid-stride per tensor
// ---------------------------------------------------------------------------
struct CvtArgs {
    const float* s[7];
    bf16* d[7];
    int n[7];
};

__global__ __launch_bounds__(256) void cvt7(CvtArgs a) {
    const int which = blockIdx.y;
    const int n = a.n[which];
    const float* __restrict__ s = a.s[which];
    bf16* __restrict__ d = a.d[which];
    for (int i = (blockIdx.x * 256 + threadIdx.x) * 8; i < n; i += 512 * 256 * 8) {
        const float4 v0 = *(const float4*)(s + i);
        const float4 v1 = *(const float4*)(s + i + 4);
        bf16x8 o = {(bf16)v0.x, (bf16)v0.y, (bf16)v0.z, (bf16)v0.w,
                    (bf16)v1.x, (bf16)v1.y, (bf16)v1.z, (bf16)v1.w};
        *(bf16x8*)(d + i) = o;
    }
}

// ---------------------------------------------------------------------------
// mask int32 [S][S] -> bf16 [S][S] with 4-way column interleave per 64-group:
// Mr[row][g*64 + l15*4 + ch] = mask[row][g*64 + ch*16 + l15]
// so an attn lane reads its 4 chunk-values (cols kt+ch*16+l15) as one 8B load.
// ---------------------------------------------------------------------------
__global__ __launch_bounds__(256) void mask_prep(const int* __restrict__ m,
                                                 bf16* __restrict__ Mr) {
    const int o = blockIdx.x * 256 + threadIdx.x;  // 0 .. S*S-1
    const int row = o >> 11, j = o & 2047;
    const int g = j >> 6, idx = j & 63;
    const int incol = (g << 6) + ((idx & 3) << 4) + (idx >> 2);
    Mr[o] = (bf16)(float)m[row * 2048 + incol];
}

// ---------------------------------------------------------------------------
// Shared GEMM K-loop: C = A @ W^T. 128x128 tile, two BK=32 sub-tiles staged
// per barrier pair (halves the vmcnt(0)+s_barrier drains), glds16 staging
// into packed stride-32 LDS (measured conflict-free), 4 waves of 64x64.
// ---------------------------------------------------------------------------
struct GemmBatch {
    const bf16* A[3];
    const bf16* W[3];
    const float* bias[3];
    bf16* out[3];
};

#define GEMM_KLOOP(Aptr, Wptr)                                                      \
    __shared__ bf16 Als[2][128 * 32];                                               \
    __shared__ bf16 Bls[2][128 * 32];                                               \
    const int tid  = threadIdx.x;                                                   \
    const int wave = tid >> 6;                                                      \
    const int lane = tid & 63;                                                      \
    const int l15  = lane & 15;                                                     \
    const int quad = lane >> 4;                                                     \
    const int m0   = blockIdx.y * 128;                                              \
    const int n0   = blockIdx.x * 128;                                              \
    const int wm   = (wave >> 1) * 64;                                              \
    const int wn   = (wave & 1) * 64;                                               \
    f32x4v acc[4][4];                                                               \
    _Pragma("unroll") for (int i = 0; i < 4; ++i)                                   \
        _Pragma("unroll") for (int j = 0; j < 4; ++j)                               \
            acc[i][j] = (f32x4v){0.f, 0.f, 0.f, 0.f};                               \
    const int r_a    = wave * 16 + (lane >> 2);                                     \
    const int c_a    = (lane & 3) * 8;                                              \
    const int ldsoff = wave * 512;                                                  \
    for (int k0 = 0; k0 < 1024; k0 += 64) {                                         \
        __syncthreads();                                                            \
        _Pragma("unroll") for (int ks = 0; ks < 2; ++ks) {                          \
            _Pragma("unroll") for (int p = 0; p < 2; ++p) {                         \
                const int row = p * 64 + r_a;                                       \
                glds16(Aptr + (size_t)(m0 + row) * 1024 + k0 + ks * 32 + c_a,       \
                       &Als[ks][p * 2048 + ldsoff]);                                \
                glds16(Wptr + (size_t)(n0 + row) * 1024 + k0 + ks * 32 + c_a,       \
                       &Bls[ks][p * 2048 + ldsoff]);                                \
            }                                                                       \
        }                                                                           \
        __syncthreads();                                                            \
        _Pragma("unroll") for (int ks = 0; ks < 2; ++ks) {                          \
            bf16x8 af[4], bfr[4];                                                   \
            _Pragma("unroll") for (int i = 0; i < 4; ++i)                           \
                af[i] = *(const bf16x8*)(                                           \
                    &Als[ks][(wm + i * 16 + l15) * 32 + quad * 8]);                 \
            _Pragma("unroll") for (int j = 0; j < 4; ++j)                           \
                bfr[j] = *(const bf16x8*)(                                          \
                    &Bls[ks][(wn + j * 16 + l15) * 32 + quad * 8]);                 \
            _Pragma("unroll") for (int i = 0; i < 4; ++i)                           \
                _Pragma("unroll") for (int j = 0; j < 4; ++j)                       \
                    acc[i][j] = MFMA16(af[i], bfr[j], acc[i][j]);                   \
        }                                                                           \
    }

// Fused Q/K/V projection: blockIdx.z selects. z<2 -> head-major [b][h][s][dk];
// z==2 -> V^T [b][h][dk][s].
__global__ __launch_bounds__(256) void gemm_qkv(GemmBatch g) {
    const int z = blockIdx.z;
    const bf16* __restrict__ A = g.A[z];
    const bf16* __restrict__ W = g.W[z];
    GEMM_KLOOP(A, W)
    const float* __restrict__ bias = g.bias[z];
    bf16* __restrict__ out = g.out[z];
#pragma unroll
    for (int j = 0; j < 4; ++j) {
        const int col = n0 + wn + j * 16 + l15;
        const float bs = bias[col];
        const int h = col >> 6, dk = col & 63;
#pragma unroll
        for (int i = 0; i < 4; ++i) {
            const int r4 = m0 + wm + i * 16 + quad * 4;
            const int b = r4 >> 11, sb = r4 & 2047;
            if (z == 2) {
                bf16x4 v = {(bf16)(acc[i][j][0] + bs), (bf16)(acc[i][j][1] + bs),
                            (bf16)(acc[i][j][2] + bs), (bf16)(acc[i][j][3] + bs)};
                *(bf16x4*)(&out[((size_t)((b * NH + h) * 64 + dk)) * SEQ + sb]) = v;
            } else {
#pragma unroll
                for (int reg = 0; reg < 4; ++reg)
                    out[((size_t)(b * NH + h) * SEQ + sb + reg) * 64 + dk] =
                        (bf16)(acc[i][j][reg] + bs);
            }
        }
    }
}

// Output projection: fp32 row-major
__global__ __launch_bounds__(256) void gemm_o(const bf16* __restrict__ A,
                                              const bf16* __restrict__ W,
                                              const float* __restrict__ bias,
                                              float* __restrict__ out) {
    GEMM_KLOOP(A, W)
#pragma unroll
    for (int j = 0; j < 4; ++j) {
        const int col = n0 + wn + j * 16 + l15;
        const float bs = bias[col];
#pragma unroll
        for (int i = 0; i < 4; ++i) {
            const int r4 = m0 + wm + i * 16 + quad * 4;
#pragma unroll
            for (int reg = 0; reg < 4; ++reg)
                out[(size_t)(r4 + reg) * 1024 + col] = acc[i][j][reg] + bs;
        }
    }
}

// ---------------------------------------------------------------------------
// Flash attention — R2 inner structure (measured best), halved q-block for
// 2x occupancy: 4 waves x 32 q-rows = 128 q/block, grid 1024 = 4 blocks/CU.
// Key tiles of 64, chunk-major K/V LDS via glds16 (measured conflict-free),
// fixed-max softmax e = exp2(s*CLOG)*mask (exact: scores bounded), P via
// same-wave LDS round-trip. LDS 34 KB, VGPR ~100 (no spill).
// ---------------------------------------------------------------------------
__global__ __launch_bounds__(256) void attn_kernel(const bf16* __restrict__ Qh,
                                                   const bf16* __restrict__ Kh,
                                                   const bf16* __restrict__ Vtg,
                                                   const bf16* __restrict__ Mr,
                                                   bf16* __restrict__ Xout) {
    __shared__ bf16 Kls[4096];      // [kc=d/8][key 0..63][8]   8 KB
    __shared__ bf16 Vls[4096];      // [sc=s/8][d 0..63][8]     8 KB
    __shared__ bf16 Pls[128 * 72];  // 4 waves x 32 q-rows, 64 keys + pad  18 KB

    const int tid  = threadIdx.x;
    const int wave = tid >> 6;
    const int lane = tid & 63;
    const int l15  = lane & 15;
    const int quad = lane >> 4;
    const int bh   = blockIdx.x;
    const int q0   = blockIdx.y * 128;

    const size_t base = (size_t)bh * SEQ * DK;
    const bf16* Q  = Qh + base;
    const bf16* K  = Kh + base;
    const bf16* Vg = Vtg + base;  // [64][SEQ]

    const int qw = q0 + wave * 32;
    // Q A-frags: [rb][kk], m = l15, k = kk*32 + quad*8 + j
    bf16x8 aq[2][2];
#pragma unroll
    for (int rb = 0; rb < 2; ++rb)
#pragma unroll
        for (int kk = 0; kk < 2; ++kk)
            aq[rb][kk] = *(const bf16x8*)(Q + (size_t)(qw + rb * 16 + l15) * 64 +
                                          kk * 32 + quad * 8);

    f32x4v acc[2][4];  // [rb][nt]
    float lsum[2][4];  // [rb][reg]
#pragma unroll
    for (int rb = 0; rb < 2; ++rb)
#pragma unroll
        for (int x = 0; x < 4; ++x) {
            acc[rb][x] = (f32x4v){0.f, 0.f, 0.f, 0.f};
            lsum[rb][x] = 0.f;
        }

    constexpr float CLOG = 0.125f * 1.4426950408889634f;  // 1/sqrt(dk)*log2(e)
    const bf16* mrow = Mr + (size_t)(qw + quad * 4) * 2048 + l15 * 4;

    for (int kt = 0; kt < SEQ; kt += 64) {
        __syncthreads();
#pragma unroll
        for (int p = 0; p < 2; ++p) {
            const int kc = wave * 2 + p;
            glds16(K + (size_t)(kt + lane) * 64 + kc * 8, &Kls[kc * 512]);
            glds16(Vg + (size_t)lane * SEQ + kt + kc * 8, &Vls[kc * 512]);
        }
        // mask values (issued before the barrier's vmcnt drain)
        bf16x4 mv[2][4];
#pragma unroll
        for (int rb = 0; rb < 2; ++rb)
#pragma unroll
            for (int reg = 0; reg < 4; ++reg)
                mv[rb][reg] = *(const bf16x4*)(mrow + (size_t)(rb * 16 + reg) * 2048 + kt);
        __syncthreads();

        // K B-frags (shared across the wave's row-blocks)
        bf16x8 bk[4][2];
#pragma unroll
        for (int n16 = 0; n16 < 4; ++n16)
#pragma unroll
            for (int kk = 0; kk < 2; ++kk)
                bk[n16][kk] = *(const bf16x8*)(
                    &Kls[(kk * 4 + quad) * 512 + (n16 * 16 + l15) * 8]);

#pragma unroll
        for (int rb = 0; rb < 2; ++rb) {
            f32x4v sv[4];
#pragma unroll
            for (int n16 = 0; n16 < 4; ++n16) {
                f32x4v t = (f32x4v){0.f, 0.f, 0.f, 0.f};
                t = MFMA16(aq[rb][0], bk[n16][0], t);
                t = MFMA16(aq[rb][1], bk[n16][1], t);
                sv[n16] = t;
            }
            const int prow0 = wave * 32 + rb * 16 + quad * 4;
#pragma unroll
            for (int reg = 0; reg < 4; ++reg) {
#pragma unroll
                for (int n16 = 0; n16 < 4; ++n16) {
                    const float e = exp2f(sv[n16][reg] * CLOG) *
                                    (float)mv[rb][reg][n16];
                    lsum[rb][reg] += e;
                    Pls[(prow0 + reg) * 72 + n16 * 16 + l15] = (bf16)e;
                }
            }
        }

        // P A-frags (same-wave LDS round trip)
        bf16x8 pf[2][2];
#pragma unroll
        for (int rb = 0; rb < 2; ++rb)
#pragma unroll
            for (int kc2 = 0; kc2 < 2; ++kc2)
                pf[rb][kc2] = *(const bf16x8*)(
                    &Pls[(wave * 32 + rb * 16 + l15) * 72 + kc2 * 32 + quad * 8]);
        // O += P V
#pragma unroll
        for (int nt = 0; nt < 4; ++nt) {
            const bf16x8 bv0 = *(const bf16x8*)(&Vls[(quad * 64 + nt * 16 + l15) * 8]);
            const bf16x8 bv1 = *(const bf16x8*)(&Vls[((4 + quad) * 64 + nt * 16 + l15) * 8]);
#pragma unroll
            for (int rb = 0; rb < 2; ++rb) {
                acc[rb][nt] = MFMA16(pf[rb][0], bv0, acc[rb][nt]);
                acc[rb][nt] = MFMA16(pf[rb][1], bv1, acc[rb][nt]);
            }
        }
    }

    // normalize and write X row-major bf16 [B*S][D_MODEL]
    const int b = bh >> 4, h = bh & 15;
#pragma unroll
    for (int rb = 0; rb < 2; ++rb) {
        float rinv[4];
#pragma unroll
        for (int reg = 0; reg < 4; ++reg) {
            float l = lsum[rb][reg];
            l += __shfl_xor(l, 1, 16);
            l += __shfl_xor(l, 2, 16);
            l += __shfl_xor(l, 4, 16);
            l += __shfl_xor(l, 8, 16);
            rinv[reg] = 1.0f / l;
        }
#pragma unroll
        for (int nt = 0; nt < 4; ++nt)
#pragma unroll
            for (int reg = 0; reg < 4; ++reg) {
                const int sg = qw + rb * 16 + quad * 4 + reg;
                Xout[(size_t)(b * SEQ + sg) * D_MODEL + h * 64 + nt * 16 + l15] =
                    (bf16)(acc[rb][nt][reg] * rinv[reg]);
            }
    }
}

extern "C" void kernel_launch(void* const* d_in, const int* in_sizes, int n_in,
                              void* d_out, int out_size, void* d_ws, size_t ws_size,
                              hipStream_t stream) {
    const float* q    = (const float*)d_in[0];
    const float* k    = (const float*)d_in[1];
    const float* v    = (const float*)d_in[2];
    const int*   mask = (const int*)d_in[3];
    const float* Wq   = (const float*)d_in[4];
    const float* bq   = (const float*)d_in[5];
    const float* Wk   = (const float*)d_in[6];
    const float* bk   = (const float*)d_in[7];
    const float* Wv   = (const float*)d_in[8];
    const float* bv   = (const float*)d_in[9];
    const float* Wo   = (const float*)d_in[10];
    const float* bo   = (const float*)d_in[11];

    const size_t T = (size_t)BATCH * SEQ * D_MODEL;
    const size_t WN = (size_t)D_MODEL * D_MODEL;
    char* w = (char*)d_ws;
    bf16* Qh  = (bf16*)w; w += T * 2;
    bf16* Kh  = (bf16*)w; w += T * 2;
    bf16* Vt  = (bf16*)w; w += T * 2;
    bf16* Mr  = (bf16*)w; w += (size_t)SEQ * SEQ * 2;
    bf16* qb2 = (bf16*)w; w += T * 2;  // reused as attn output X
    bf16* kb2 = (bf16*)w; w += T * 2;
    bf16* vb2 = (bf16*)w; w += T * 2;
    bf16* Wqb = (bf16*)w; w += WN * 2;
    bf16* Wkb = (bf16*)w; w += WN * 2;
    bf16* Wvb = (bf16*)w; w += WN * 2;
    bf16* Wob = (bf16*)w; w += WN * 2;

    CvtArgs ca;
    ca.s[0] = q;  ca.d[0] = qb2; ca.n[0] = (int)T;
    ca.s[1] = k;  ca.d[1] = kb2; ca.n[1] = (int)T;
    ca.s[2] = v;  ca.d[2] = vb2; ca.n[2] = (int)T;
    ca.s[3] = Wq; ca.d[3] = Wqb; ca.n[3] = (int)WN;
    ca.s[4] = Wk; ca.d[4] = Wkb; ca.n[4] = (int)WN;
    ca.s[5] = Wv; ca.d[5] = Wvb; ca.n[5] = (int)WN;
    ca.s[6] = Wo; ca.d[6] = Wob; ca.n[6] = (int)WN;
    cvt7<<<dim3(512, 7), 256, 0, stream>>>(ca);
    mask_prep<<<dim3((SEQ * SEQ) / 256), 256, 0, stream>>>(mask, Mr);

    GemmBatch g;
    g.A[0] = qb2; g.W[0] = Wqb; g.bias[0] = bq; g.out[0] = Qh;
    g.A[1] = kb2; g.W[1] = Wkb; g.bias[1] = bk; g.out[1] = Kh;
    g.A[2] = vb2; g.W[2] = Wvb; g.bias[2] = bv; g.out[2] = Vt;
    gemm_qkv<<<dim3(D_MODEL / 128, (BATCH * SEQ) / 128, 3), 256, 0, stream>>>(g);

    attn_kernel<<<dim3(BATCH * NH, SEQ / 128), 256, 0, stream>>>(Qh, Kh, Vt, Mr, qb2);

    gemm_o<<<dim3(D_MODEL / 128, (BATCH * SEQ) / 128), 256, 0, stream>>>(qb2, Wob, bo,
                                                                         (float*)d_out);
}